// Round 2
// 346.419 us; speedup vs baseline: 1.1340x; 1.1340x over previous
//
#include <hip/hip_runtime.h>
#include <hip/hip_bf16.h>
#include <math.h>

#define N_NODES 100000
#define N_EDGES 1600000
#define D_IN 64
#define D_HID 64
#define D_OUT 40
#define NBUCK 256
#define BSZ 391                 // nodes per bucket; 256*391 = 100096 >= N
#define P3_EPB 4096             // edges per k_place block
#define P3_GRID ((N_EDGES + P3_EPB - 1) / P3_EPB)   // 391

typedef __hip_bfloat16 bf16;

__device__ __forceinline__ float bflo(unsigned int u) {
    union { unsigned int i; float f; } c; c.i = u << 16; return c.f;
}
__device__ __forceinline__ float bfhi(unsigned int u) {
    union { unsigned int i; float f; } c; c.i = u & 0xFFFF0000u; return c.f;
}

// ---- zero ints ----
__global__ __launch_bounds__(256) void k_zero(int* __restrict__ p, int n) {
    int i = blockIdx.x * 256 + threadIdx.x;
    if (i < n) p[i] = 0;
}

// ---- phase 1: global bucket counts (LDS histogram, padded global counters) ----
__global__ __launch_bounds__(256) void k_cnt(const int* __restrict__ col,
                                             int* __restrict__ bcnt_p) {
    __shared__ int hist[NBUCK];
    hist[threadIdx.x] = 0;
    __syncthreads();
    for (int e = blockIdx.x * 256 + threadIdx.x; e < N_EDGES; e += 256 * 256) {
        unsigned int c = (unsigned int)col[e];
        atomicAdd(&hist[c / 391u], 1);
    }
    __syncthreads();
    int hv = hist[threadIdx.x];
    if (hv) atomicAdd(&bcnt_p[threadIdx.x * 16], hv);   // 64B-strided: no line sharing
}

// ---- phase 2: scan 256 bucket counts; init fill = base ----
__global__ __launch_bounds__(256) void k_scan256(const int* __restrict__ bcnt_p,
                                                 int* __restrict__ fill_p,
                                                 int* __restrict__ bucket_base) {
    __shared__ int sm[256];
    int t = threadIdx.x;
    int v = bcnt_p[t * 16];
    sm[t] = v;
    __syncthreads();
    for (int off = 1; off < 256; off <<= 1) {
        int u = (t >= off) ? sm[t - off] : 0;
        __syncthreads();
        sm[t] += u;
        __syncthreads();
    }
    int excl = sm[t] - v;
    bucket_base[t] = excl;
    fill_p[t * 16] = excl;
    if (t == 255) bucket_base[256] = sm[255];
}

// ---- phase 3: partition edges into bucket-contiguous packed array ----
// packed part[] word: (local_c << 17) | src   (9 + 17 = 26 bits)
__global__ __launch_bounds__(256) void k_place(const int* __restrict__ ei,
                                               int* __restrict__ fill_p,
                                               int* __restrict__ part) {
    __shared__ int cnt_l[NBUCK];
    __shared__ int base_l[NBUCK];
    cnt_l[threadIdx.x] = 0;
    __syncthreads();
    int e0 = blockIdx.x * P3_EPB;
    unsigned int meta[16];                     // (b<<21)|(lc<<12)|slot
#pragma unroll
    for (int k = 0; k < 16; k++) {
        int e = e0 + k * 256 + threadIdx.x;
        if (e < N_EDGES) {
            unsigned int c = (unsigned int)ei[N_EDGES + e];
            unsigned int b = c / 391u;
            unsigned int lc = c - b * 391u;
            unsigned int slot = atomicAdd(&cnt_l[b], 1);   // slot < 4096
            meta[k] = (b << 21) | (lc << 12) | slot;
        } else meta[k] = 0xFFFFFFFFu;
    }
    __syncthreads();
    int cv = cnt_l[threadIdx.x];
    if (cv) base_l[threadIdx.x] = atomicAdd(&fill_p[threadIdx.x * 16], cv);
    __syncthreads();
#pragma unroll
    for (int k = 0; k < 16; k++) {
        if (meta[k] != 0xFFFFFFFFu) {
            int e = e0 + k * 256 + threadIdx.x;
            unsigned int b = meta[k] >> 21;
            unsigned int lc = (meta[k] >> 12) & 0x1FFu;
            unsigned int slot = meta[k] & 0xFFFu;
            unsigned int r = (unsigned int)ei[e];
            part[base_l[b] + slot] = (int)((lc << 17) | r);
        }
    }
}

// ---- phase 4: per-bucket CSR build + deg/start/dinv, all in LDS/L2 ----
__global__ __launch_bounds__(256) void k_build(const int* __restrict__ part,
                                               const int* __restrict__ bucket_base,
                                               int* __restrict__ start,
                                               float* __restrict__ dinv,
                                               int* __restrict__ csr) {
    __shared__ int deg_l[392];
    __shared__ int excl_l[392];
    int tid = threadIdx.x;
    int b = blockIdx.x;
    int base = bucket_base[b], end = bucket_base[b + 1];
    int m = end - base;
    for (int i = tid; i < 392; i += 256) deg_l[i] = 0;
    __syncthreads();
    for (int i = tid; i < m; i += 256)
        atomicAdd(&deg_l[(unsigned int)part[base + i] >> 17], 1);
    __syncthreads();
    // wave 0: exclusive scan of deg_l[0..391]
    if (tid < 64) {
        int carry = 0;
        for (int ch = 0; ch < 7; ch++) {       // 7*64 = 448 >= 392
            int idx = ch * 64 + tid;
            int val = (idx < 392) ? deg_l[idx] : 0;
            int incl = val;
#pragma unroll
            for (int off = 1; off < 64; off <<= 1) {
                int u = __shfl_up(incl, off, 64);
                if (tid >= off) incl += u;
            }
            if (idx < 392) excl_l[idx] = carry + incl - val;
            carry += __shfl(incl, 63, 64);
        }
    }
    __syncthreads();
    int v0 = b * BSZ;
    for (int vl = tid; vl < BSZ; vl += 256) {
        int v = v0 + vl;
        if (v < N_NODES) {
            start[v] = base + excl_l[vl];
            dinv[v] = rsqrtf((float)deg_l[vl] + 1.0f);
        }
    }
    if (b == NBUCK - 1 && tid == 0) start[N_NODES] = bucket_base[NBUCK];
    __syncthreads();
    for (int i = tid; i < 392; i += 256) deg_l[i] = 0;   // reuse as fill
    __syncthreads();
    for (int i = tid; i < m; i += 256) {
        unsigned int p = (unsigned int)part[base + i];
        unsigned int lc = p >> 17;
        int s = atomicAdd(&deg_l[lc], 1);
        csr[base + excl_l[lc] + s] = (int)(p & 0x1FFFFu);
    }
}

// ---- layer1 GEMM: gb[v,j] = bf16( dinv[v] * sum_k x[v,k]*W1[k,j] ) ----
__global__ __launch_bounds__(256) void k_gemm1(const float* __restrict__ x,
                                               const float* __restrict__ W,
                                               const float* __restrict__ dinv,
                                               bf16* __restrict__ gb) {
    __shared__ float Ws[64 * 64];
    __shared__ float xs[4][64];
    int tid = threadIdx.x;
    for (int i = tid; i < 64 * 64; i += 256) Ws[i] = W[i];
    int v0 = blockIdx.x * 4;
    for (int i = tid; i < 4 * 64; i += 256) xs[i >> 6][i & 63] = x[v0 * 64 + i];
    __syncthreads();
    int r = tid >> 6, j = tid & 63;
    float acc = 0.f;
#pragma unroll
    for (int k = 0; k < 64; k++) acc += xs[r][k] * Ws[k * 64 + j];
    int v = v0 + r;
    gb[v * 64 + j] = __float2bfloat16(acc * dinv[v]);
}

// ---- agg1: 16-lane edge-groups, uint2 (4xbf16) gathers; WAVE-UNIFORM trip count
//      (shfl needs all source lanes active on CDNA); bias + ReLU -> h ----
__global__ __launch_bounds__(256) void k_agg1(const int* __restrict__ csr,
                                              const int* __restrict__ start,
                                              const unsigned int* __restrict__ gb2,
                                              const float* __restrict__ dinv,
                                              const float* __restrict__ b1,
                                              float* __restrict__ h) {
    int lane = threadIdx.x & 63;
    int g = lane >> 4;          // 4 edge-groups of 16 lanes; group g -> edges 4*i+g
    int lq = lane & 15;         // 8B slice lq of the 128B row (cols 4lq..4lq+3)
    int v = blockIdx.x * 4 + (threadIdx.x >> 6);
    int s = start[v], e2 = start[v + 1];
    float a0 = 0.f, a1 = 0.f, a2 = 0.f, a3 = 0.f;
    if (g == 0) {               // self-loop contribution
        uint2 u = *(const uint2*)(gb2 + (size_t)v * 32 + lq * 2);
        a0 += bflo(u.x); a1 += bfhi(u.x);
        a2 += bflo(u.y); a3 += bfhi(u.y);
    }
    for (int base = s; base < e2; base += 64) {
        int cnt = e2 - base; if (cnt > 64) cnt = 64;
        int rl = (lane < cnt) ? csr[base + lane] : 0;
        int ni = (cnt + 3) >> 2;               // wave-uniform (cnt is uniform)
        for (int i = 0; i < ni; i++) {
            int idx = 4 * i + g;
            int r = __shfl(rl, idx, 64);       // all 64 lanes active here
            if (idx < cnt) {
                uint2 u = *(const uint2*)(gb2 + (size_t)r * 32 + lq * 2);
                a0 += bflo(u.x); a1 += bfhi(u.x);
                a2 += bflo(u.y); a3 += bfhi(u.y);
            }
        }
    }
    // fold the 4 edge-groups
    a0 += __shfl_xor(a0, 16, 64); a1 += __shfl_xor(a1, 16, 64);
    a2 += __shfl_xor(a2, 16, 64); a3 += __shfl_xor(a3, 16, 64);
    a0 += __shfl_xor(a0, 32, 64); a1 += __shfl_xor(a1, 32, 64);
    a2 += __shfl_xor(a2, 32, 64); a3 += __shfl_xor(a3, 32, 64);
    float d = dinv[v];
    float4 bb = ((const float4*)b1)[lq];
    float h0 = fmaxf(d * a0 + bb.x, 0.f);
    float h1 = fmaxf(d * a1 + bb.y, 0.f);
    float h2 = fmaxf(d * a2 + bb.z, 0.f);
    float h3 = fmaxf(d * a3 + bb.w, 0.f);
    if (g == 0)
        ((float4*)(h + (size_t)v * 64))[lq] = make_float4(h0, h1, h2, h3);
}

// ---- layer2 GEMM: g2b[v,j] = bf16( dinv[v] * sum_k h[v,k]*W2[k,j] ) ----
__global__ __launch_bounds__(256) void k_gemm2(const float* __restrict__ h,
                                               const float* __restrict__ W,
                                               const float* __restrict__ dinv,
                                               bf16* __restrict__ g2b) {
    __shared__ float Ws[64 * 40];
    __shared__ float hs[4][64];
    int tid = threadIdx.x;
    for (int i = tid; i < 64 * 40; i += 256) Ws[i] = W[i];
    int v0 = blockIdx.x * 4;
    for (int i = tid; i < 4 * 64; i += 256) hs[i >> 6][i & 63] = h[v0 * 64 + i];
    __syncthreads();
    int r = tid >> 6, j = tid & 63;
    if (j < 40) {
        float acc = 0.f;
#pragma unroll
        for (int k = 0; k < 64; k++) acc += hs[r][k] * Ws[k * 40 + j];
        int v = v0 + r;
        g2b[v * 40 + j] = __float2bfloat16(acc * dinv[v]);
    }
}

// ---- agg2: 16-lane edge-groups (10 active lanes), uint2 gathers; WAVE-UNIFORM
//      trip count; fused bias + log_softmax -> out ----
__global__ __launch_bounds__(256) void k_agg2(const int* __restrict__ csr,
                                              const int* __restrict__ start,
                                              const unsigned int* __restrict__ g2b2,
                                              const float* __restrict__ dinv,
                                              const float* __restrict__ b2v,
                                              float* __restrict__ out) {
    int lane = threadIdx.x & 63;
    int g = lane >> 4;          // 4 edge-groups of 16 lanes
    int lq = lane & 15;         // 8B slice of the 80B row; active lq<10
    int v = blockIdx.x * 4 + (threadIdx.x >> 6);
    int s = start[v], e2 = start[v + 1];
    bool act = (lq < 10);
    float a0 = 0.f, a1 = 0.f, a2 = 0.f, a3 = 0.f;
    if (g == 0 && act) {        // self-loop contribution
        uint2 u = *(const uint2*)(g2b2 + (size_t)v * 20 + lq * 2);
        a0 += bflo(u.x); a1 += bfhi(u.x);
        a2 += bflo(u.y); a3 += bfhi(u.y);
    }
    for (int base = s; base < e2; base += 64) {
        int cnt = e2 - base; if (cnt > 64) cnt = 64;
        int rl = (lane < cnt) ? csr[base + lane] : 0;
        int ni = (cnt + 3) >> 2;               // wave-uniform (cnt is uniform)
        for (int i = 0; i < ni; i++) {
            int idx = 4 * i + g;
            int r = __shfl(rl, idx, 64);       // all 64 lanes active here
            if (act && idx < cnt) {
                uint2 u = *(const uint2*)(g2b2 + (size_t)r * 20 + lq * 2);
                a0 += bflo(u.x); a1 += bfhi(u.x);
                a2 += bflo(u.y); a3 += bfhi(u.y);
            }
        }
    }
    // fold the 4 edge-groups
    a0 += __shfl_xor(a0, 16, 64); a1 += __shfl_xor(a1, 16, 64);
    a2 += __shfl_xor(a2, 16, 64); a3 += __shfl_xor(a3, 16, 64);
    a0 += __shfl_xor(a0, 32, 64); a1 += __shfl_xor(a1, 32, 64);
    a2 += __shfl_xor(a2, 32, 64); a3 += __shfl_xor(a3, 32, 64);
    float d = dinv[v];
    float4 bb = act ? ((const float4*)b2v)[lq] : make_float4(0.f, 0.f, 0.f, 0.f);
    float lx0 = act ? d * a0 + bb.x : -INFINITY;
    float lx1 = act ? d * a1 + bb.y : -INFINITY;
    float lx2 = act ? d * a2 + bb.z : -INFINITY;
    float lx3 = act ? d * a3 + bb.w : -INFINITY;
    float m = fmaxf(fmaxf(lx0, lx1), fmaxf(lx2, lx3));
#pragma unroll
    for (int o = 1; o < 16; o <<= 1) m = fmaxf(m, __shfl_xor(m, o, 64));
    float ex = act ? (__expf(lx0 - m) + __expf(lx1 - m) +
                      __expf(lx2 - m) + __expf(lx3 - m)) : 0.f;
#pragma unroll
    for (int o = 1; o < 16; o <<= 1) ex += __shfl_xor(ex, o, 64);
    float lse = m + logf(ex);
    if (g == 0 && act)
        ((float4*)(out + (size_t)v * 40))[lq] =
            make_float4(lx0 - lse, lx1 - lse, lx2 - lse, lx3 - lse);
}

extern "C" void kernel_launch(void* const* d_in, const int* in_sizes, int n_in,
                              void* d_out, int out_size, void* d_ws, size_t ws_size,
                              hipStream_t stream) {
    const float* x  = (const float*)d_in[0];
    const int*   ei = (const int*)d_in[1];
    const float* W1 = (const float*)d_in[2];
    const float* b1 = (const float*)d_in[3];
    const float* W2 = (const float*)d_in[4];
    const float* b2 = (const float*)d_in[5];
    float* out = (float*)d_out;

    const int N = N_NODES;
    // Workspace layout (ints from base), total ~52 MB:
    int*   part  = (int*)d_ws;                  // E      packed partitioned edges
    int*   csr   = part + N_EDGES;              // E
    int*   start = csr + N_EDGES;               // N+2 (padded even)
    int*   bcnt  = start + N + 2;               // 256*16 padded counters
    int*   fill  = bcnt + 4096;                 // 256*16 padded counters
    int*   bbase = fill + 4096;                 // 257 (+pad -> 258)
    float* dinv  = (float*)(bbase + 258);       // N
    float* h     = dinv + N;                    // N*64 fp32 (16B-aligned)
    bf16*  gb    = (bf16*)(h + (size_t)N * 64); // N*64 bf16 (g1; reused g2 N*40)

    k_zero<<<16, 256, 0, stream>>>(bcnt, 4096);
    k_cnt<<<256, 256, 0, stream>>>(ei + N_EDGES, bcnt);
    k_scan256<<<1, 256, 0, stream>>>(bcnt, fill, bbase);
    k_place<<<P3_GRID, 256, 0, stream>>>(ei, fill, part);
    k_build<<<NBUCK, 256, 0, stream>>>(part, bbase, start, dinv, csr);
    k_gemm1<<<N / 4, 256, 0, stream>>>(x, W1, dinv, gb);
    k_agg1<<<N / 4, 256, 0, stream>>>(csr, start, (const unsigned int*)gb, dinv, b1, h);
    k_gemm2<<<N / 4, 256, 0, stream>>>(h, W2, dinv, gb);
    k_agg2<<<N / 4, 256, 0, stream>>>(csr, start, (const unsigned int*)gb, dinv, b2, out);
}

// Round 3
// 275.625 us; speedup vs baseline: 1.4252x; 1.2569x over previous
//
#include <hip/hip_runtime.h>
#include <hip/hip_bf16.h>
#include <math.h>

#define N_NODES 100000
#define N_EDGES 1600000
#define D_IN 64
#define D_HID 64
#define D_OUT 40
#define NBUCK 256
#define BSZ 391                 // nodes per bucket; 256*391 = 100096 >= N
#define P3_EPB 4096             // edges per k_place block
#define P3_GRID ((N_EDGES + P3_EPB - 1) / P3_EPB)   // 391
#define GEMM_GRID ((N_NODES + 63) / 64)             // 1563 blocks, 16 nodes/wave

typedef __hip_bfloat16 bf16;
typedef __attribute__((ext_vector_type(8))) short short8;
typedef __attribute__((ext_vector_type(4))) float f32x4;

__device__ __forceinline__ float bflo(unsigned int u) {
    union { unsigned int i; float f; } c; c.i = u << 16; return c.f;
}
__device__ __forceinline__ float bfhi(unsigned int u) {
    union { unsigned int i; float f; } c; c.i = u & 0xFFFF0000u; return c.f;
}
// fp32 -> bf16 bits, round-to-nearest-even (finite inputs)
__device__ __forceinline__ unsigned short f2b(float f) {
    union { float f; unsigned int u; } c; c.f = f;
    unsigned int u = c.u + 0x7FFFu + ((c.u >> 16) & 1u);
    return (unsigned short)(u >> 16);
}

// ---- zero ints ----
__global__ __launch_bounds__(256) void k_zero(int* __restrict__ p, int n) {
    int i = blockIdx.x * 256 + threadIdx.x;
    if (i < n) p[i] = 0;
}

// ---- phase 1: global bucket counts (LDS histogram, padded global counters) ----
__global__ __launch_bounds__(256) void k_cnt(const int* __restrict__ col,
                                             int* __restrict__ bcnt_p) {
    __shared__ int hist[NBUCK];
    hist[threadIdx.x] = 0;
    __syncthreads();
    for (int e = blockIdx.x * 256 + threadIdx.x; e < N_EDGES; e += 256 * 256) {
        unsigned int c = (unsigned int)col[e];
        atomicAdd(&hist[c / 391u], 1);
    }
    __syncthreads();
    int hv = hist[threadIdx.x];
    if (hv) atomicAdd(&bcnt_p[threadIdx.x * 16], hv);   // 64B-strided: no line sharing
}

// ---- phase 2: scan 256 bucket counts; init fill = base ----
__global__ __launch_bounds__(256) void k_scan256(const int* __restrict__ bcnt_p,
                                                 int* __restrict__ fill_p,
                                                 int* __restrict__ bucket_base) {
    __shared__ int sm[256];
    int t = threadIdx.x;
    int v = bcnt_p[t * 16];
    sm[t] = v;
    __syncthreads();
    for (int off = 1; off < 256; off <<= 1) {
        int u = (t >= off) ? sm[t - off] : 0;
        __syncthreads();
        sm[t] += u;
        __syncthreads();
    }
    int excl = sm[t] - v;
    bucket_base[t] = excl;
    fill_p[t * 16] = excl;
    if (t == 255) bucket_base[256] = sm[255];
}

// ---- phase 3: partition edges into bucket-contiguous packed array ----
// packed part[] word: (local_c << 17) | src   (9 + 17 = 26 bits)
__global__ __launch_bounds__(256) void k_place(const int* __restrict__ ei,
                                               int* __restrict__ fill_p,
                                               int* __restrict__ part) {
    __shared__ int cnt_l[NBUCK];
    __shared__ int base_l[NBUCK];
    cnt_l[threadIdx.x] = 0;
    __syncthreads();
    int e0 = blockIdx.x * P3_EPB;
    unsigned int meta[16];                     // (b<<21)|(lc<<12)|slot
#pragma unroll
    for (int k = 0; k < 16; k++) {
        int e = e0 + k * 256 + threadIdx.x;
        if (e < N_EDGES) {
            unsigned int c = (unsigned int)ei[N_EDGES + e];
            unsigned int b = c / 391u;
            unsigned int lc = c - b * 391u;
            unsigned int slot = atomicAdd(&cnt_l[b], 1);   // slot < 4096
            meta[k] = (b << 21) | (lc << 12) | slot;
        } else meta[k] = 0xFFFFFFFFu;
    }
    __syncthreads();
    int cv = cnt_l[threadIdx.x];
    if (cv) base_l[threadIdx.x] = atomicAdd(&fill_p[threadIdx.x * 16], cv);
    __syncthreads();
#pragma unroll
    for (int k = 0; k < 16; k++) {
        if (meta[k] != 0xFFFFFFFFu) {
            int e = e0 + k * 256 + threadIdx.x;
            unsigned int b = meta[k] >> 21;
            unsigned int lc = (meta[k] >> 12) & 0x1FFu;
            unsigned int slot = meta[k] & 0xFFFu;
            unsigned int r = (unsigned int)ei[e];
            part[base_l[b] + slot] = (int)((lc << 17) | r);
        }
    }
}

// ---- phase 4: per-bucket CSR build + deg/start/dinv, all in LDS/L2 ----
__global__ __launch_bounds__(256) void k_build(const int* __restrict__ part,
                                               const int* __restrict__ bucket_base,
                                               int* __restrict__ start,
                                               float* __restrict__ dinv,
                                               int* __restrict__ csr) {
    __shared__ int deg_l[392];
    __shared__ int excl_l[392];
    int tid = threadIdx.x;
    int b = blockIdx.x;
    int base = bucket_base[b], end = bucket_base[b + 1];
    int m = end - base;
    for (int i = tid; i < 392; i += 256) deg_l[i] = 0;
    __syncthreads();
    for (int i = tid; i < m; i += 256)
        atomicAdd(&deg_l[(unsigned int)part[base + i] >> 17], 1);
    __syncthreads();
    // wave 0: exclusive scan of deg_l[0..391]
    if (tid < 64) {
        int carry = 0;
        for (int ch = 0; ch < 7; ch++) {       // 7*64 = 448 >= 392
            int idx = ch * 64 + tid;
            int val = (idx < 392) ? deg_l[idx] : 0;
            int incl = val;
#pragma unroll
            for (int off = 1; off < 64; off <<= 1) {
                int u = __shfl_up(incl, off, 64);
                if (tid >= off) incl += u;
            }
            if (idx < 392) excl_l[idx] = carry + incl - val;
            carry += __shfl(incl, 63, 64);
        }
    }
    __syncthreads();
    int v0 = b * BSZ;
    for (int vl = tid; vl < BSZ; vl += 256) {
        int v = v0 + vl;
        if (v < N_NODES) {
            start[v] = base + excl_l[vl];
            dinv[v] = rsqrtf((float)deg_l[vl] + 1.0f);
        }
    }
    if (b == NBUCK - 1 && tid == 0) start[N_NODES] = bucket_base[NBUCK];
    __syncthreads();
    for (int i = tid; i < 392; i += 256) deg_l[i] = 0;   // reuse as fill
    __syncthreads();
    for (int i = tid; i < m; i += 256) {
        unsigned int p = (unsigned int)part[base + i];
        unsigned int lc = p >> 17;
        int s = atomicAdd(&deg_l[lc], 1);
        csr[base + excl_l[lc] + s] = (int)(p & 0x1FFFFu);
    }
}

// ---- prep: pack W1/W2 (fp32) into per-lane bf16 MFMA A-fragments ----
// A-fragment layout for mfma_f32_16x16x32_bf16 with A = W^T tile:
//   frag index f = (kk*NJT + jt); wp[(f*64 + lane)*8 + e] =
//     W[kk*32 + (lane>>4)*8 + e][jt*16 + (lane&15)]   (0 if col >= JW)
__global__ __launch_bounds__(256) void k_prep(const float* __restrict__ W1,
                                              const float* __restrict__ W2,
                                              unsigned short* __restrict__ wp1,
                                              unsigned short* __restrict__ wp2) {
    int tid = threadIdx.x;
    for (int i = tid; i < 4096; i += 256) {           // 2 kk * 4 jt * 64 lane * 8 e
        int e = i & 7, lane = (i >> 3) & 63, t = i >> 9;
        int kk = t >> 2, jt = t & 3;
        int row = kk * 32 + (lane >> 4) * 8 + e;
        int col = jt * 16 + (lane & 15);
        wp1[i] = f2b(W1[row * 64 + col]);
    }
    for (int i = tid; i < 3072; i += 256) {           // 2 kk * 3 jt * 64 lane * 8 e
        int e = i & 7, lane = (i >> 3) & 63, t = i >> 9;
        int kk = t / 3, jt = t - kk * 3;
        int row = kk * 32 + (lane >> 4) * 8 + e;
        int col = jt * 16 + (lane & 15);
        wp2[i] = (col < 40) ? f2b(W2[row * 40 + col]) : (unsigned short)0;
    }
}

// ---- layer1 GEMM via MFMA: gb[v][j] = bf16(dinv[v] * (x @ W1)[v][j]) ----
// Wave computes 16 nodes x 64 cols. D = A(W^T) * B(x^T): D col = node, row = j.
__global__ __launch_bounds__(256) void k_gemm1m(const float* __restrict__ x,
                                                const short8* __restrict__ wp,
                                                const float* __restrict__ dinv,
                                                unsigned short* __restrict__ gb) {
    int lane = threadIdx.x & 63;
    int wid = threadIdx.x >> 6;
    int node0 = (blockIdx.x * 4 + wid) * 16;
    if (node0 >= N_NODES) return;
    int vr = node0 + (lane & 15);
    if (vr >= N_NODES) vr = N_NODES - 1;               // defensive (unreachable)
    int kg = lane >> 4;
    const float* px = x + (size_t)vr * 64 + kg * 8;
    short8 b0, b1;
    {
        float4 f0 = *(const float4*)px;
        float4 f1 = *(const float4*)(px + 4);
        b0[0] = (short)f2b(f0.x); b0[1] = (short)f2b(f0.y);
        b0[2] = (short)f2b(f0.z); b0[3] = (short)f2b(f0.w);
        b0[4] = (short)f2b(f1.x); b0[5] = (short)f2b(f1.y);
        b0[6] = (short)f2b(f1.z); b0[7] = (short)f2b(f1.w);
        float4 g0 = *(const float4*)(px + 32);
        float4 g1 = *(const float4*)(px + 36);
        b1[0] = (short)f2b(g0.x); b1[1] = (short)f2b(g0.y);
        b1[2] = (short)f2b(g0.z); b1[3] = (short)f2b(g0.w);
        b1[4] = (short)f2b(g1.x); b1[5] = (short)f2b(g1.y);
        b1[6] = (short)f2b(g1.z); b1[7] = (short)f2b(g1.w);
    }
    f32x4 acc[4];
#pragma unroll
    for (int jt = 0; jt < 4; jt++) acc[jt] = (f32x4){0.f, 0.f, 0.f, 0.f};
#pragma unroll
    for (int jt = 0; jt < 4; jt++) {
        acc[jt] = __builtin_amdgcn_mfma_f32_16x16x32_bf16(
            wp[(0 * 4 + jt) * 64 + lane], b0, acc[jt], 0, 0, 0);
        acc[jt] = __builtin_amdgcn_mfma_f32_16x16x32_bf16(
            wp[(1 * 4 + jt) * 64 + lane], b1, acc[jt], 0, 0, 0);
    }
    float d = dinv[vr];
    unsigned short* gp = gb + (size_t)vr * 64 + kg * 4;
#pragma unroll
    for (int jt = 0; jt < 4; jt++) {
        unsigned int lo = (unsigned int)f2b(acc[jt][0] * d) |
                          ((unsigned int)f2b(acc[jt][1] * d) << 16);
        unsigned int hi = (unsigned int)f2b(acc[jt][2] * d) |
                          ((unsigned int)f2b(acc[jt][3] * d) << 16);
        *(uint2*)(gp + jt * 16) = make_uint2(lo, hi);
    }
}

// ---- layer2 GEMM via MFMA: gb[v][j<40] = bf16(dinv[v] * (h @ W2)[v][j]) ----
// h is bf16 (hb), so B-fragments are direct 16B loads.
__global__ __launch_bounds__(256) void k_gemm2m(const unsigned short* __restrict__ hb,
                                                const short8* __restrict__ wp,
                                                const float* __restrict__ dinv,
                                                unsigned short* __restrict__ gb) {
    int lane = threadIdx.x & 63;
    int wid = threadIdx.x >> 6;
    int node0 = (blockIdx.x * 4 + wid) * 16;
    if (node0 >= N_NODES) return;
    int vr = node0 + (lane & 15);
    if (vr >= N_NODES) vr = N_NODES - 1;
    int kg = lane >> 4;
    const short8* h8 = (const short8*)hb;
    short8 b0 = h8[(size_t)vr * 8 + kg];
    short8 b1 = h8[(size_t)vr * 8 + 4 + kg];
    f32x4 acc[3];
#pragma unroll
    for (int jt = 0; jt < 3; jt++) acc[jt] = (f32x4){0.f, 0.f, 0.f, 0.f};
#pragma unroll
    for (int jt = 0; jt < 3; jt++) {
        acc[jt] = __builtin_amdgcn_mfma_f32_16x16x32_bf16(
            wp[(0 * 3 + jt) * 64 + lane], b0, acc[jt], 0, 0, 0);
        acc[jt] = __builtin_amdgcn_mfma_f32_16x16x32_bf16(
            wp[(1 * 3 + jt) * 64 + lane], b1, acc[jt], 0, 0, 0);
    }
    float d = dinv[vr];
    unsigned short* gp = gb + (size_t)vr * 40 + kg * 4;
#pragma unroll
    for (int jt = 0; jt < 3; jt++) {
        if (jt == 2 && kg >= 2) break;                 // j >= 40
        unsigned int lo = (unsigned int)f2b(acc[jt][0] * d) |
                          ((unsigned int)f2b(acc[jt][1] * d) << 16);
        unsigned int hi = (unsigned int)f2b(acc[jt][2] * d) |
                          ((unsigned int)f2b(acc[jt][3] * d) << 16);
        *(uint2*)(gp + jt * 16) = make_uint2(lo, hi);
    }
}

// ---- agg1: 16-lane edge-groups, uint2 (4xbf16) gathers; WAVE-UNIFORM trip count
//      (shfl needs all source lanes active on CDNA); bias + ReLU -> hb (bf16) ----
__global__ __launch_bounds__(256) void k_agg1(const int* __restrict__ csr,
                                              const int* __restrict__ start,
                                              const unsigned int* __restrict__ gb2,
                                              const float* __restrict__ dinv,
                                              const float* __restrict__ b1,
                                              unsigned short* __restrict__ hb) {
    int lane = threadIdx.x & 63;
    int g = lane >> 4;          // 4 edge-groups of 16 lanes; group g -> edges 4*i+g
    int lq = lane & 15;         // 8B slice lq of the 128B row (cols 4lq..4lq+3)
    int v = blockIdx.x * 4 + (threadIdx.x >> 6);
    int s = start[v], e2 = start[v + 1];
    float a0 = 0.f, a1 = 0.f, a2 = 0.f, a3 = 0.f;
    if (g == 0) {               // self-loop contribution
        uint2 u = *(const uint2*)(gb2 + (size_t)v * 32 + lq * 2);
        a0 += bflo(u.x); a1 += bfhi(u.x);
        a2 += bflo(u.y); a3 += bfhi(u.y);
    }
    for (int base = s; base < e2; base += 64) {
        int cnt = e2 - base; if (cnt > 64) cnt = 64;
        int rl = (lane < cnt) ? csr[base + lane] : 0;
        int ni = (cnt + 3) >> 2;               // wave-uniform (cnt is uniform)
        for (int i = 0; i < ni; i++) {
            int idx = 4 * i + g;
            int r = __shfl(rl, idx, 64);       // all 64 lanes active here
            if (idx < cnt) {
                uint2 u = *(const uint2*)(gb2 + (size_t)r * 32 + lq * 2);
                a0 += bflo(u.x); a1 += bfhi(u.x);
                a2 += bflo(u.y); a3 += bfhi(u.y);
            }
        }
    }
    // fold the 4 edge-groups
    a0 += __shfl_xor(a0, 16, 64); a1 += __shfl_xor(a1, 16, 64);
    a2 += __shfl_xor(a2, 16, 64); a3 += __shfl_xor(a3, 16, 64);
    a0 += __shfl_xor(a0, 32, 64); a1 += __shfl_xor(a1, 32, 64);
    a2 += __shfl_xor(a2, 32, 64); a3 += __shfl_xor(a3, 32, 64);
    float d = dinv[v];
    float4 bb = ((const float4*)b1)[lq];
    float h0 = fmaxf(d * a0 + bb.x, 0.f);
    float h1 = fmaxf(d * a1 + bb.y, 0.f);
    float h2 = fmaxf(d * a2 + bb.z, 0.f);
    float h3 = fmaxf(d * a3 + bb.w, 0.f);
    if (g == 0) {
        unsigned int lo = (unsigned int)f2b(h0) | ((unsigned int)f2b(h1) << 16);
        unsigned int hi = (unsigned int)f2b(h2) | ((unsigned int)f2b(h3) << 16);
        *(uint2*)(hb + (size_t)v * 64 + lq * 4) = make_uint2(lo, hi);
    }
}

// ---- agg2: 16-lane edge-groups (10 active lanes), uint2 gathers; WAVE-UNIFORM
//      trip count; fused bias + log_softmax -> out ----
__global__ __launch_bounds__(256) void k_agg2(const int* __restrict__ csr,
                                              const int* __restrict__ start,
                                              const unsigned int* __restrict__ g2b2,
                                              const float* __restrict__ dinv,
                                              const float* __restrict__ b2v,
                                              float* __restrict__ out) {
    int lane = threadIdx.x & 63;
    int g = lane >> 4;          // 4 edge-groups of 16 lanes
    int lq = lane & 15;         // 8B slice of the 80B row; active lq<10
    int v = blockIdx.x * 4 + (threadIdx.x >> 6);
    int s = start[v], e2 = start[v + 1];
    bool act = (lq < 10);
    float a0 = 0.f, a1 = 0.f, a2 = 0.f, a3 = 0.f;
    if (g == 0 && act) {        // self-loop contribution
        uint2 u = *(const uint2*)(g2b2 + (size_t)v * 20 + lq * 2);
        a0 += bflo(u.x); a1 += bfhi(u.x);
        a2 += bflo(u.y); a3 += bfhi(u.y);
    }
    for (int base = s; base < e2; base += 64) {
        int cnt = e2 - base; if (cnt > 64) cnt = 64;
        int rl = (lane < cnt) ? csr[base + lane] : 0;
        int ni = (cnt + 3) >> 2;               // wave-uniform (cnt is uniform)
        for (int i = 0; i < ni; i++) {
            int idx = 4 * i + g;
            int r = __shfl(rl, idx, 64);       // all 64 lanes active here
            if (act && idx < cnt) {
                uint2 u = *(const uint2*)(g2b2 + (size_t)r * 20 + lq * 2);
                a0 += bflo(u.x); a1 += bfhi(u.x);
                a2 += bflo(u.y); a3 += bfhi(u.y);
            }
        }
    }
    // fold the 4 edge-groups
    a0 += __shfl_xor(a0, 16, 64); a1 += __shfl_xor(a1, 16, 64);
    a2 += __shfl_xor(a2, 16, 64); a3 += __shfl_xor(a3, 16, 64);
    a0 += __shfl_xor(a0, 32, 64); a1 += __shfl_xor(a1, 32, 64);
    a2 += __shfl_xor(a2, 32, 64); a3 += __shfl_xor(a3, 32, 64);
    float d = dinv[v];
    float4 bb = act ? ((const float4*)b2v)[lq] : make_float4(0.f, 0.f, 0.f, 0.f);
    float lx0 = act ? d * a0 + bb.x : -INFINITY;
    float lx1 = act ? d * a1 + bb.y : -INFINITY;
    float lx2 = act ? d * a2 + bb.z : -INFINITY;
    float lx3 = act ? d * a3 + bb.w : -INFINITY;
    float m = fmaxf(fmaxf(lx0, lx1), fmaxf(lx2, lx3));
#pragma unroll
    for (int o = 1; o < 16; o <<= 1) m = fmaxf(m, __shfl_xor(m, o, 64));
    float ex = act ? (__expf(lx0 - m) + __expf(lx1 - m) +
                      __expf(lx2 - m) + __expf(lx3 - m)) : 0.f;
#pragma unroll
    for (int o = 1; o < 16; o <<= 1) ex += __shfl_xor(ex, o, 64);
    float lse = m + logf(ex);
    if (g == 0 && act)
        ((float4*)(out + (size_t)v * 40))[lq] =
            make_float4(lx0 - lse, lx1 - lse, lx2 - lse, lx3 - lse);
}

extern "C" void kernel_launch(void* const* d_in, const int* in_sizes, int n_in,
                              void* d_out, int out_size, void* d_ws, size_t ws_size,
                              hipStream_t stream) {
    const float* x  = (const float*)d_in[0];
    const int*   ei = (const int*)d_in[1];
    const float* W1 = (const float*)d_in[2];
    const float* b1 = (const float*)d_in[3];
    const float* W2 = (const float*)d_in[4];
    const float* b2 = (const float*)d_in[5];
    float* out = (float*)d_out;

    const int N = N_NODES;
    // Workspace layout (ints from base), total ~39.3 MB:
    int*   part  = (int*)d_ws;                  // E      packed partitioned edges
    int*   csr   = part + N_EDGES;              // E
    int*   start = csr + N_EDGES;               // N+2 (padded even)
    int*   bcnt  = start + N + 2;               // 256*16 padded counters
    int*   fill  = bcnt + 4096;                 // 256*16 padded counters
    int*   bbase = fill + 4096;                 // 257 (+pad -> 258)
    float* dinv  = (float*)(bbase + 258);       // N (16B-aligned)
    unsigned short* hb  = (unsigned short*)(dinv + N);   // N*64 bf16 (16B-aligned)
    unsigned short* gb  = hb + (size_t)N * 64;           // N*64 bf16 (g1; reused g2 N*40)
    unsigned short* wp1 = gb + (size_t)N * 64;           // 4096 bf16 W1 fragments
    unsigned short* wp2 = wp1 + 4096;                    // 3072 bf16 W2 fragments

    k_zero<<<16, 256, 0, stream>>>(bcnt, 4096);
    k_prep<<<1, 256, 0, stream>>>(W1, W2, wp1, wp2);
    k_cnt<<<256, 256, 0, stream>>>(ei + N_EDGES, bcnt);
    k_scan256<<<1, 256, 0, stream>>>(bcnt, fill, bbase);
    k_place<<<P3_GRID, 256, 0, stream>>>(ei, fill, part);
    k_build<<<NBUCK, 256, 0, stream>>>(part, bbase, start, dinv, csr);
    k_gemm1m<<<GEMM_GRID, 256, 0, stream>>>(x, (const short8*)wp1, dinv, gb);
    k_agg1<<<N / 4, 256, 0, stream>>>(csr, start, (const unsigned int*)gb, dinv, b1, hb);
    k_gemm2m<<<GEMM_GRID, 256, 0, stream>>>(hb, (const short8*)wp2, dinv, gb);
    k_agg2<<<N / 4, 256, 0, stream>>>(csr, start, (const unsigned int*)gb, dinv, b2, out);
}

// Round 4
// 270.990 us; speedup vs baseline: 1.4496x; 1.0171x over previous
//
#include <hip/hip_runtime.h>
#include <hip/hip_bf16.h>
#include <math.h>

#define N_NODES 100000
#define N_EDGES 1600000
#define D_IN 64
#define D_HID 64
#define D_OUT 40
#define NBUCK 256
#define BSZ 391                 // nodes per bucket; 256*391 = 100096 >= N
#define P3_EPB 4096             // edges per k_place block
#define P3_GRID ((N_EDGES + P3_EPB - 1) / P3_EPB)   // 391
#define GEMM_GRID ((N_NODES + 63) / 64)             // 1563 blocks, 16 nodes/wave

typedef __hip_bfloat16 bf16;
typedef __attribute__((ext_vector_type(8))) short short8;
typedef __attribute__((ext_vector_type(4))) float f32x4;

__device__ __forceinline__ float bflo(unsigned int u) {
    union { unsigned int i; float f; } c; c.i = u << 16; return c.f;
}
__device__ __forceinline__ float bfhi(unsigned int u) {
    union { unsigned int i; float f; } c; c.i = u & 0xFFFF0000u; return c.f;
}
// fp32 -> bf16 bits, round-to-nearest-even (finite inputs)
__device__ __forceinline__ unsigned short f2b(float f) {
    union { float f; unsigned int u; } c; c.f = f;
    unsigned int u = c.u + 0x7FFFu + ((c.u >> 16) & 1u);
    return (unsigned short)(u >> 16);
}

// ---- zero ints ----
__global__ __launch_bounds__(256) void k_zero(int* __restrict__ p, int n) {
    int i = blockIdx.x * 256 + threadIdx.x;
    if (i < n) p[i] = 0;
}

// ---- phase 1: global bucket counts (LDS histogram, padded global counters) ----
__global__ __launch_bounds__(256) void k_cnt(const int* __restrict__ col,
                                             int* __restrict__ bcnt_p) {
    __shared__ int hist[NBUCK];
    hist[threadIdx.x] = 0;
    __syncthreads();
    for (int e = blockIdx.x * 256 + threadIdx.x; e < N_EDGES; e += 256 * 256) {
        unsigned int c = (unsigned int)col[e];
        atomicAdd(&hist[c / 391u], 1);
    }
    __syncthreads();
    int hv = hist[threadIdx.x];
    if (hv) atomicAdd(&bcnt_p[threadIdx.x * 16], hv);   // 64B-strided: no line sharing
}

// ---- phase 2: scan 256 bucket counts; init fill = base ----
__global__ __launch_bounds__(256) void k_scan256(const int* __restrict__ bcnt_p,
                                                 int* __restrict__ fill_p,
                                                 int* __restrict__ bucket_base) {
    __shared__ int sm[256];
    int t = threadIdx.x;
    int v = bcnt_p[t * 16];
    sm[t] = v;
    __syncthreads();
    for (int off = 1; off < 256; off <<= 1) {
        int u = (t >= off) ? sm[t - off] : 0;
        __syncthreads();
        sm[t] += u;
        __syncthreads();
    }
    int excl = sm[t] - v;
    bucket_base[t] = excl;
    fill_p[t * 16] = excl;
    if (t == 255) bucket_base[256] = sm[255];
}

// ---- phase 3: partition edges into bucket-contiguous packed array ----
// packed part[] word: (local_c << 17) | src   (9 + 17 = 26 bits)
__global__ __launch_bounds__(256) void k_place(const int* __restrict__ ei,
                                               int* __restrict__ fill_p,
                                               int* __restrict__ part) {
    __shared__ int cnt_l[NBUCK];
    __shared__ int base_l[NBUCK];
    cnt_l[threadIdx.x] = 0;
    __syncthreads();
    int e0 = blockIdx.x * P3_EPB;
    unsigned int meta[16];                     // (b<<21)|(lc<<12)|slot
#pragma unroll
    for (int k = 0; k < 16; k++) {
        int e = e0 + k * 256 + threadIdx.x;
        if (e < N_EDGES) {
            unsigned int c = (unsigned int)ei[N_EDGES + e];
            unsigned int b = c / 391u;
            unsigned int lc = c - b * 391u;
            unsigned int slot = atomicAdd(&cnt_l[b], 1);   // slot < 4096
            meta[k] = (b << 21) | (lc << 12) | slot;
        } else meta[k] = 0xFFFFFFFFu;
    }
    __syncthreads();
    int cv = cnt_l[threadIdx.x];
    if (cv) base_l[threadIdx.x] = atomicAdd(&fill_p[threadIdx.x * 16], cv);
    __syncthreads();
#pragma unroll
    for (int k = 0; k < 16; k++) {
        if (meta[k] != 0xFFFFFFFFu) {
            int e = e0 + k * 256 + threadIdx.x;
            unsigned int b = meta[k] >> 21;
            unsigned int lc = (meta[k] >> 12) & 0x1FFu;
            unsigned int slot = meta[k] & 0xFFFu;
            unsigned int r = (unsigned int)ei[e];
            part[base_l[b] + slot] = (int)((lc << 17) | r);
        }
    }
}

// ---- phase 4: per-bucket CSR build + deg/start/dinv, all in LDS/L2 ----
__global__ __launch_bounds__(256) void k_build(const int* __restrict__ part,
                                               const int* __restrict__ bucket_base,
                                               int* __restrict__ start,
                                               float* __restrict__ dinv,
                                               int* __restrict__ csr) {
    __shared__ int deg_l[392];
    __shared__ int excl_l[392];
    int tid = threadIdx.x;
    int b = blockIdx.x;
    int base = bucket_base[b], end = bucket_base[b + 1];
    int m = end - base;
    for (int i = tid; i < 392; i += 256) deg_l[i] = 0;
    __syncthreads();
    for (int i = tid; i < m; i += 256)
        atomicAdd(&deg_l[(unsigned int)part[base + i] >> 17], 1);
    __syncthreads();
    // wave 0: exclusive scan of deg_l[0..391]
    if (tid < 64) {
        int carry = 0;
        for (int ch = 0; ch < 7; ch++) {       // 7*64 = 448 >= 392
            int idx = ch * 64 + tid;
            int val = (idx < 392) ? deg_l[idx] : 0;
            int incl = val;
#pragma unroll
            for (int off = 1; off < 64; off <<= 1) {
                int u = __shfl_up(incl, off, 64);
                if (tid >= off) incl += u;
            }
            if (idx < 392) excl_l[idx] = carry + incl - val;
            carry += __shfl(incl, 63, 64);
        }
    }
    __syncthreads();
    int v0 = b * BSZ;
    for (int vl = tid; vl < BSZ; vl += 256) {
        int v = v0 + vl;
        if (v < N_NODES) {
            start[v] = base + excl_l[vl];
            dinv[v] = rsqrtf((float)deg_l[vl] + 1.0f);
        }
    }
    if (b == NBUCK - 1 && tid == 0) start[N_NODES] = bucket_base[NBUCK];
    __syncthreads();
    for (int i = tid; i < 392; i += 256) deg_l[i] = 0;   // reuse as fill
    __syncthreads();
    for (int i = tid; i < m; i += 256) {
        unsigned int p = (unsigned int)part[base + i];
        unsigned int lc = p >> 17;
        int s = atomicAdd(&deg_l[lc], 1);
        csr[base + excl_l[lc] + s] = (int)(p & 0x1FFFFu);
    }
}

// ---- prep: pack W1/W2 (fp32) into per-lane bf16 MFMA A-fragments ----
// A-fragment layout for mfma_f32_16x16x32_bf16 with A = W^T tile:
//   frag index f = (kk*NJT + jt); wp[(f*64 + lane)*8 + e] =
//     W[kk*32 + (lane>>4)*8 + e][jt*16 + (lane&15)]   (0 if col >= JW)
__global__ __launch_bounds__(256) void k_prep(const float* __restrict__ W1,
                                              const float* __restrict__ W2,
                                              unsigned short* __restrict__ wp1,
                                              unsigned short* __restrict__ wp2) {
    int tid = threadIdx.x;
    for (int i = tid; i < 4096; i += 256) {           // 2 kk * 4 jt * 64 lane * 8 e
        int e = i & 7, lane = (i >> 3) & 63, t = i >> 9;
        int kk = t >> 2, jt = t & 3;
        int row = kk * 32 + (lane >> 4) * 8 + e;
        int col = jt * 16 + (lane & 15);
        wp1[i] = f2b(W1[row * 64 + col]);
    }
    for (int i = tid; i < 3072; i += 256) {           // 2 kk * 3 jt * 64 lane * 8 e
        int e = i & 7, lane = (i >> 3) & 63, t = i >> 9;
        int kk = t / 3, jt = t - kk * 3;
        int row = kk * 32 + (lane >> 4) * 8 + e;
        int col = jt * 16 + (lane & 15);
        wp2[i] = (col < 40) ? f2b(W2[row * 40 + col]) : (unsigned short)0;
    }
}

// ---- layer1 GEMM via MFMA: gb[v][j] = bf16(dinv[v] * (x @ W1)[v][j]) ----
// Wave computes 16 nodes x 64 cols. D = A(W^T) * B(x^T): D col = node, row = j.
__global__ __launch_bounds__(256) void k_gemm1m(const float* __restrict__ x,
                                                const short8* __restrict__ wp,
                                                const float* __restrict__ dinv,
                                                unsigned short* __restrict__ gb) {
    int lane = threadIdx.x & 63;
    int wid = threadIdx.x >> 6;
    int node0 = (blockIdx.x * 4 + wid) * 16;
    if (node0 >= N_NODES) return;
    int vr = node0 + (lane & 15);
    if (vr >= N_NODES) vr = N_NODES - 1;               // defensive (unreachable)
    int kg = lane >> 4;
    const float* px = x + (size_t)vr * 64 + kg * 8;
    short8 b0, b1;
    {
        float4 f0 = *(const float4*)px;
        float4 f1 = *(const float4*)(px + 4);
        b0[0] = (short)f2b(f0.x); b0[1] = (short)f2b(f0.y);
        b0[2] = (short)f2b(f0.z); b0[3] = (short)f2b(f0.w);
        b0[4] = (short)f2b(f1.x); b0[5] = (short)f2b(f1.y);
        b0[6] = (short)f2b(f1.z); b0[7] = (short)f2b(f1.w);
        float4 g0 = *(const float4*)(px + 32);
        float4 g1 = *(const float4*)(px + 36);
        b1[0] = (short)f2b(g0.x); b1[1] = (short)f2b(g0.y);
        b1[2] = (short)f2b(g0.z); b1[3] = (short)f2b(g0.w);
        b1[4] = (short)f2b(g1.x); b1[5] = (short)f2b(g1.y);
        b1[6] = (short)f2b(g1.z); b1[7] = (short)f2b(g1.w);
    }
    f32x4 acc[4];
#pragma unroll
    for (int jt = 0; jt < 4; jt++) acc[jt] = (f32x4){0.f, 0.f, 0.f, 0.f};
#pragma unroll
    for (int jt = 0; jt < 4; jt++) {
        acc[jt] = __builtin_amdgcn_mfma_f32_16x16x32_bf16(
            wp[(0 * 4 + jt) * 64 + lane], b0, acc[jt], 0, 0, 0);
        acc[jt] = __builtin_amdgcn_mfma_f32_16x16x32_bf16(
            wp[(1 * 4 + jt) * 64 + lane], b1, acc[jt], 0, 0, 0);
    }
    float d = dinv[vr];
    unsigned short* gp = gb + (size_t)vr * 64 + kg * 4;
#pragma unroll
    for (int jt = 0; jt < 4; jt++) {
        unsigned int lo = (unsigned int)f2b(acc[jt][0] * d) |
                          ((unsigned int)f2b(acc[jt][1] * d) << 16);
        unsigned int hi = (unsigned int)f2b(acc[jt][2] * d) |
                          ((unsigned int)f2b(acc[jt][3] * d) << 16);
        *(uint2*)(gp + jt * 16) = make_uint2(lo, hi);
    }
}

// ---- layer2 GEMM via MFMA: gb[v][j<40] = bf16(dinv[v] * (h @ W2)[v][j]) ----
// h is bf16 (hb), so B-fragments are direct 16B loads.
__global__ __launch_bounds__(256) void k_gemm2m(const unsigned short* __restrict__ hb,
                                                const short8* __restrict__ wp,
                                                const float* __restrict__ dinv,
                                                unsigned short* __restrict__ gb) {
    int lane = threadIdx.x & 63;
    int wid = threadIdx.x >> 6;
    int node0 = (blockIdx.x * 4 + wid) * 16;
    if (node0 >= N_NODES) return;
    int vr = node0 + (lane & 15);
    if (vr >= N_NODES) vr = N_NODES - 1;
    int kg = lane >> 4;
    const short8* h8 = (const short8*)hb;
    short8 b0 = h8[(size_t)vr * 8 + kg];
    short8 b1 = h8[(size_t)vr * 8 + 4 + kg];
    f32x4 acc[3];
#pragma unroll
    for (int jt = 0; jt < 3; jt++) acc[jt] = (f32x4){0.f, 0.f, 0.f, 0.f};
#pragma unroll
    for (int jt = 0; jt < 3; jt++) {
        acc[jt] = __builtin_amdgcn_mfma_f32_16x16x32_bf16(
            wp[(0 * 3 + jt) * 64 + lane], b0, acc[jt], 0, 0, 0);
        acc[jt] = __builtin_amdgcn_mfma_f32_16x16x32_bf16(
            wp[(1 * 3 + jt) * 64 + lane], b1, acc[jt], 0, 0, 0);
    }
    float d = dinv[vr];
    unsigned short* gp = gb + (size_t)vr * 40 + kg * 4;
#pragma unroll
    for (int jt = 0; jt < 3; jt++) {
        if (jt == 2 && kg >= 2) break;                 // j >= 40
        unsigned int lo = (unsigned int)f2b(acc[jt][0] * d) |
                          ((unsigned int)f2b(acc[jt][1] * d) << 16);
        unsigned int hi = (unsigned int)f2b(acc[jt][2] * d) |
                          ((unsigned int)f2b(acc[jt][3] * d) << 16);
        *(uint2*)(gp + jt * 16) = make_uint2(lo, hi);
    }
}

// ---- agg1: 8-lane edge-groups, uint4 (8xbf16) gathers, DIRECT csr loads
//      (no shfl: deg is wave-uniform, group lanes broadcast-load same csr word);
//      unroll-2 for MLP; bias + ReLU -> hb (bf16) ----
__global__ __launch_bounds__(256) void k_agg1(const int* __restrict__ csr,
                                              const int* __restrict__ start,
                                              const unsigned int* __restrict__ gb2,
                                              const float* __restrict__ dinv,
                                              const float* __restrict__ b1,
                                              unsigned short* __restrict__ hb) {
    int lane = threadIdx.x & 63;
    int g = lane >> 3;          // 8 edge-groups of 8 lanes; group g -> edges 8*k+g
    int lq = lane & 7;          // 16B slice lq of the 128B row (cols 8lq..8lq+7)
    int v = blockIdx.x * 4 + (threadIdx.x >> 6);
    int s = start[v], e2 = start[v + 1];
    int deg = e2 - s;
    float a0=0.f,a1=0.f,a2=0.f,a3=0.f,a4=0.f,a5=0.f,a6=0.f,a7=0.f;
    if (g == 0) {               // self-loop contribution
        uint4 u = *(const uint4*)(gb2 + (size_t)v * 32 + lq * 4);
        a0 += bflo(u.x); a1 += bfhi(u.x); a2 += bflo(u.y); a3 += bfhi(u.y);
        a4 += bflo(u.z); a5 += bfhi(u.z); a6 += bflo(u.w); a7 += bfhi(u.w);
    }
    int nk = (deg + 7) >> 3;    // wave-uniform trip count
#pragma unroll 2
    for (int k = 0; k < nk; k++) {
        int idx = k * 8 + g;
        if (idx < deg) {
            int r = csr[s + idx];                       // 8-lane broadcast load
            uint4 u = *(const uint4*)(gb2 + (size_t)r * 32 + lq * 4);
            a0 += bflo(u.x); a1 += bfhi(u.x); a2 += bflo(u.y); a3 += bfhi(u.y);
            a4 += bflo(u.z); a5 += bfhi(u.z); a6 += bflo(u.w); a7 += bfhi(u.w);
        }
    }
    // fold the 8 edge-groups (all 64 lanes active at every shfl)
#pragma unroll
    for (int o = 8; o < 64; o <<= 1) {
        a0 += __shfl_xor(a0, o, 64); a1 += __shfl_xor(a1, o, 64);
        a2 += __shfl_xor(a2, o, 64); a3 += __shfl_xor(a3, o, 64);
        a4 += __shfl_xor(a4, o, 64); a5 += __shfl_xor(a5, o, 64);
        a6 += __shfl_xor(a6, o, 64); a7 += __shfl_xor(a7, o, 64);
    }
    float d = dinv[v];
    float4 bb0 = ((const float4*)b1)[lq * 2];
    float4 bb1 = ((const float4*)b1)[lq * 2 + 1];
    float h0 = fmaxf(d * a0 + bb0.x, 0.f), h1 = fmaxf(d * a1 + bb0.y, 0.f);
    float h2 = fmaxf(d * a2 + bb0.z, 0.f), h3 = fmaxf(d * a3 + bb0.w, 0.f);
    float h4 = fmaxf(d * a4 + bb1.x, 0.f), h5 = fmaxf(d * a5 + bb1.y, 0.f);
    float h6 = fmaxf(d * a6 + bb1.z, 0.f), h7 = fmaxf(d * a7 + bb1.w, 0.f);
    if (g == 0) {
        uint4 o;
        o.x = (unsigned int)f2b(h0) | ((unsigned int)f2b(h1) << 16);
        o.y = (unsigned int)f2b(h2) | ((unsigned int)f2b(h3) << 16);
        o.z = (unsigned int)f2b(h4) | ((unsigned int)f2b(h5) << 16);
        o.w = (unsigned int)f2b(h6) | ((unsigned int)f2b(h7) << 16);
        *(uint4*)(hb + (size_t)v * 64 + lq * 8) = o;
    }
}

// ---- agg2: 8-lane edge-groups (5 active: 5x16B = 80B row), uint4 gathers,
//      DIRECT csr loads, unroll-2; fused bias + log_softmax -> out ----
__global__ __launch_bounds__(256) void k_agg2(const int* __restrict__ csr,
                                              const int* __restrict__ start,
                                              const unsigned int* __restrict__ g2b2,
                                              const float* __restrict__ dinv,
                                              const float* __restrict__ b2v,
                                              float* __restrict__ out) {
    int lane = threadIdx.x & 63;
    int g = lane >> 3;          // 8 edge-groups of 8 lanes
    int lq = lane & 7;          // 16B slice of the 80B row; active lq<5
    int v = blockIdx.x * 4 + (threadIdx.x >> 6);
    int s = start[v], e2 = start[v + 1];
    int deg = e2 - s;
    bool act = (lq < 5);
    float a0=0.f,a1=0.f,a2=0.f,a3=0.f,a4=0.f,a5=0.f,a6=0.f,a7=0.f;
    if (g == 0 && act) {        // self-loop contribution
        uint4 u = *(const uint4*)(g2b2 + (size_t)v * 20 + lq * 4);
        a0 += bflo(u.x); a1 += bfhi(u.x); a2 += bflo(u.y); a3 += bfhi(u.y);
        a4 += bflo(u.z); a5 += bfhi(u.z); a6 += bflo(u.w); a7 += bfhi(u.w);
    }
    int nk = (deg + 7) >> 3;    // wave-uniform trip count
#pragma unroll 2
    for (int k = 0; k < nk; k++) {
        int idx = k * 8 + g;
        if (act && idx < deg) {
            int r = csr[s + idx];                       // broadcast load
            uint4 u = *(const uint4*)(g2b2 + (size_t)r * 20 + lq * 4);
            a0 += bflo(u.x); a1 += bfhi(u.x); a2 += bflo(u.y); a3 += bfhi(u.y);
            a4 += bflo(u.z); a5 += bfhi(u.z); a6 += bflo(u.w); a7 += bfhi(u.w);
        }
    }
    // fold the 8 edge-groups (all 64 lanes active at every shfl)
#pragma unroll
    for (int o = 8; o < 64; o <<= 1) {
        a0 += __shfl_xor(a0, o, 64); a1 += __shfl_xor(a1, o, 64);
        a2 += __shfl_xor(a2, o, 64); a3 += __shfl_xor(a3, o, 64);
        a4 += __shfl_xor(a4, o, 64); a5 += __shfl_xor(a5, o, 64);
        a6 += __shfl_xor(a6, o, 64); a7 += __shfl_xor(a7, o, 64);
    }
    float d = dinv[v];
    float4 bb0 = act ? ((const float4*)b2v)[lq * 2] : make_float4(0.f,0.f,0.f,0.f);
    float4 bb1 = act ? ((const float4*)b2v)[lq * 2 + 1] : make_float4(0.f,0.f,0.f,0.f);
    float l0 = act ? d * a0 + bb0.x : -INFINITY;
    float l1 = act ? d * a1 + bb0.y : -INFINITY;
    float l2 = act ? d * a2 + bb0.z : -INFINITY;
    float l3 = act ? d * a3 + bb0.w : -INFINITY;
    float l4 = act ? d * a4 + bb1.x : -INFINITY;
    float l5 = act ? d * a5 + bb1.y : -INFINITY;
    float l6 = act ? d * a6 + bb1.z : -INFINITY;
    float l7 = act ? d * a7 + bb1.w : -INFINITY;
    float m = fmaxf(fmaxf(fmaxf(l0, l1), fmaxf(l2, l3)),
                    fmaxf(fmaxf(l4, l5), fmaxf(l6, l7)));
#pragma unroll
    for (int o = 1; o < 8; o <<= 1) m = fmaxf(m, __shfl_xor(m, o, 64));
    float ex = act ? (__expf(l0 - m) + __expf(l1 - m) + __expf(l2 - m) +
                      __expf(l3 - m) + __expf(l4 - m) + __expf(l5 - m) +
                      __expf(l6 - m) + __expf(l7 - m)) : 0.f;
#pragma unroll
    for (int o = 1; o < 8; o <<= 1) ex += __shfl_xor(ex, o, 64);
    float lse = m + logf(ex);
    if (g == 0 && act) {
        float* op = out + (size_t)v * 40 + lq * 8;
        *(float4*)op = make_float4(l0 - lse, l1 - lse, l2 - lse, l3 - lse);
        *(float4*)(op + 4) = make_float4(l4 - lse, l5 - lse, l6 - lse, l7 - lse);
    }
}

extern "C" void kernel_launch(void* const* d_in, const int* in_sizes, int n_in,
                              void* d_out, int out_size, void* d_ws, size_t ws_size,
                              hipStream_t stream) {
    const float* x  = (const float*)d_in[0];
    const int*   ei = (const int*)d_in[1];
    const float* W1 = (const float*)d_in[2];
    const float* b1 = (const float*)d_in[3];
    const float* W2 = (const float*)d_in[4];
    const float* b2 = (const float*)d_in[5];
    float* out = (float*)d_out;

    const int N = N_NODES;
    // Workspace layout (ints from base), total ~39.3 MB:
    int*   part  = (int*)d_ws;                  // E      packed partitioned edges
    int*   csr   = part + N_EDGES;              // E
    int*   start = csr + N_EDGES;               // N+2 (padded even)
    int*   bcnt  = start + N + 2;               // 256*16 padded counters
    int*   fill  = bcnt + 4096;                 // 256*16 padded counters
    int*   bbase = fill + 4096;                 // 257 (+pad -> 258)
    float* dinv  = (float*)(bbase + 258);       // N (16B-aligned)
    unsigned short* hb  = (unsigned short*)(dinv + N);   // N*64 bf16 (16B-aligned)
    unsigned short* gb  = hb + (size_t)N * 64;           // N*64 bf16 (g1; reused g2 N*40)
    unsigned short* wp1 = gb + (size_t)N * 64;           // 4096 bf16 W1 fragments
    unsigned short* wp2 = wp1 + 4096;                    // 3072 bf16 W2 fragments

    k_zero<<<16, 256, 0, stream>>>(bcnt, 4096);
    k_prep<<<1, 256, 0, stream>>>(W1, W2, wp1, wp2);
    k_cnt<<<256, 256, 0, stream>>>(ei + N_EDGES, bcnt);
    k_scan256<<<1, 256, 0, stream>>>(bcnt, fill, bbase);
    k_place<<<P3_GRID, 256, 0, stream>>>(ei, fill, part);
    k_build<<<NBUCK, 256, 0, stream>>>(part, bbase, start, dinv, csr);
    k_gemm1m<<<GEMM_GRID, 256, 0, stream>>>(x, (const short8*)wp1, dinv, gb);
    k_agg1<<<N / 4, 256, 0, stream>>>(csr, start, (const unsigned int*)gb, dinv, b1, hb);
    k_gemm2m<<<GEMM_GRID, 256, 0, stream>>>(hb, (const short8*)wp2, dinv, gb);
    k_agg2<<<N / 4, 256, 0, stream>>>(csr, start, (const unsigned int*)gb, dinv, b2, out);
}

// Round 5
// 257.347 us; speedup vs baseline: 1.5265x; 1.0530x over previous
//
#include <hip/hip_runtime.h>
#include <hip/hip_bf16.h>
#include <math.h>

#define N_NODES 100000
#define N_EDGES 1600000
#define D_IN 64
#define D_HID 64
#define D_OUT 40
#define NBUCK 256
#define BSZ 391                 // nodes per bucket; 256*391 = 100096 >= N
#define P3_EPB 4096             // edges per k_place block
#define P3_GRID ((N_EDGES + P3_EPB - 1) / P3_EPB)   // 391
#define GEMM_GRID ((N_NODES + 63) / 64)             // 1563 blocks, 16 nodes/wave

typedef __hip_bfloat16 bf16;
typedef __attribute__((ext_vector_type(8))) short short8;
typedef __attribute__((ext_vector_type(4))) float f32x4;

__device__ __forceinline__ float bflo(unsigned int u) {
    union { unsigned int i; float f; } c; c.i = u << 16; return c.f;
}
__device__ __forceinline__ float bfhi(unsigned int u) {
    union { unsigned int i; float f; } c; c.i = u & 0xFFFF0000u; return c.f;
}
// fp32 -> bf16 bits, round-to-nearest-even (finite inputs)
__device__ __forceinline__ unsigned short f2b(float f) {
    union { float f; unsigned int u; } c; c.f = f;
    unsigned int u = c.u + 0x7FFFu + ((c.u >> 16) & 1u);
    return (unsigned short)(u >> 16);
}

// ---- zero ints ----
__global__ __launch_bounds__(256) void k_zero(int* __restrict__ p, int n) {
    int i = blockIdx.x * 256 + threadIdx.x;
    if (i < n) p[i] = 0;
}

// ---- phase 1: global bucket counts (LDS histogram, padded global counters) ----
__global__ __launch_bounds__(256) void k_cnt(const int* __restrict__ col,
                                             int* __restrict__ bcnt_p) {
    __shared__ int hist[NBUCK];
    hist[threadIdx.x] = 0;
    __syncthreads();
    for (int e = blockIdx.x * 256 + threadIdx.x; e < N_EDGES; e += 256 * 256) {
        unsigned int c = (unsigned int)col[e];
        atomicAdd(&hist[c / 391u], 1);
    }
    __syncthreads();
    int hv = hist[threadIdx.x];
    if (hv) atomicAdd(&bcnt_p[threadIdx.x * 16], hv);   // 64B-strided: no line sharing
}

// ---- phase 2: scan 256 bucket counts; init fill = base ----
__global__ __launch_bounds__(256) void k_scan256(const int* __restrict__ bcnt_p,
                                                 int* __restrict__ fill_p,
                                                 int* __restrict__ bucket_base) {
    __shared__ int sm[256];
    int t = threadIdx.x;
    int v = bcnt_p[t * 16];
    sm[t] = v;
    __syncthreads();
    for (int off = 1; off < 256; off <<= 1) {
        int u = (t >= off) ? sm[t - off] : 0;
        __syncthreads();
        sm[t] += u;
        __syncthreads();
    }
    int excl = sm[t] - v;
    bucket_base[t] = excl;
    fill_p[t * 16] = excl;
    if (t == 255) bucket_base[256] = sm[255];
}

// ---- phase 3: partition edges into bucket-contiguous packed array ----
// packed part[] word: (local_c << 17) | src   (9 + 17 = 26 bits)
__global__ __launch_bounds__(256) void k_place(const int* __restrict__ ei,
                                               int* __restrict__ fill_p,
                                               int* __restrict__ part) {
    __shared__ int cnt_l[NBUCK];
    __shared__ int base_l[NBUCK];
    cnt_l[threadIdx.x] = 0;
    __syncthreads();
    int e0 = blockIdx.x * P3_EPB;
    unsigned int meta[16];                     // (b<<21)|(lc<<12)|slot
#pragma unroll
    for (int k = 0; k < 16; k++) {
        int e = e0 + k * 256 + threadIdx.x;
        if (e < N_EDGES) {
            unsigned int c = (unsigned int)ei[N_EDGES + e];
            unsigned int b = c / 391u;
            unsigned int lc = c - b * 391u;
            unsigned int slot = atomicAdd(&cnt_l[b], 1);   // slot < 4096
            meta[k] = (b << 21) | (lc << 12) | slot;
        } else meta[k] = 0xFFFFFFFFu;
    }
    __syncthreads();
    int cv = cnt_l[threadIdx.x];
    if (cv) base_l[threadIdx.x] = atomicAdd(&fill_p[threadIdx.x * 16], cv);
    __syncthreads();
#pragma unroll
    for (int k = 0; k < 16; k++) {
        if (meta[k] != 0xFFFFFFFFu) {
            int e = e0 + k * 256 + threadIdx.x;
            unsigned int b = meta[k] >> 21;
            unsigned int lc = (meta[k] >> 12) & 0x1FFu;
            unsigned int slot = meta[k] & 0xFFFu;
            unsigned int r = (unsigned int)ei[e];
            part[base_l[b] + slot] = (int)((lc << 17) | r);
        }
    }
}

// ---- phase 4: per-bucket CSR build + deg/start/dinv, all in LDS/L2 ----
__global__ __launch_bounds__(256) void k_build(const int* __restrict__ part,
                                               const int* __restrict__ bucket_base,
                                               int* __restrict__ start,
                                               float* __restrict__ dinv,
                                               int* __restrict__ csr) {
    __shared__ int deg_l[392];
    __shared__ int excl_l[392];
    int tid = threadIdx.x;
    int b = blockIdx.x;
    int base = bucket_base[b], end = bucket_base[b + 1];
    int m = end - base;
    for (int i = tid; i < 392; i += 256) deg_l[i] = 0;
    __syncthreads();
    for (int i = tid; i < m; i += 256)
        atomicAdd(&deg_l[(unsigned int)part[base + i] >> 17], 1);
    __syncthreads();
    // wave 0: exclusive scan of deg_l[0..391]
    if (tid < 64) {
        int carry = 0;
        for (int ch = 0; ch < 7; ch++) {       // 7*64 = 448 >= 392
            int idx = ch * 64 + tid;
            int val = (idx < 392) ? deg_l[idx] : 0;
            int incl = val;
#pragma unroll
            for (int off = 1; off < 64; off <<= 1) {
                int u = __shfl_up(incl, off, 64);
                if (tid >= off) incl += u;
            }
            if (idx < 392) excl_l[idx] = carry + incl - val;
            carry += __shfl(incl, 63, 64);
        }
    }
    __syncthreads();
    int v0 = b * BSZ;
    for (int vl = tid; vl < BSZ; vl += 256) {
        int v = v0 + vl;
        if (v < N_NODES) {
            start[v] = base + excl_l[vl];
            dinv[v] = rsqrtf((float)deg_l[vl] + 1.0f);
        }
    }
    if (b == NBUCK - 1 && tid == 0) start[N_NODES] = bucket_base[NBUCK];
    __syncthreads();
    for (int i = tid; i < 392; i += 256) deg_l[i] = 0;   // reuse as fill
    __syncthreads();
    for (int i = tid; i < m; i += 256) {
        unsigned int p = (unsigned int)part[base + i];
        unsigned int lc = p >> 17;
        int s = atomicAdd(&deg_l[lc], 1);
        csr[base + excl_l[lc] + s] = (int)(p & 0x1FFFFu);
    }
}

// ---- prep: pack W1/W2 (fp32) into per-lane bf16 MFMA A-fragments ----
// A-fragment layout for mfma_f32_16x16x32_bf16 with A = W^T tile:
//   frag index f = (kk*NJT + jt); wp[(f*64 + lane)*8 + e] =
//     W[kk*32 + (lane>>4)*8 + e][jt*16 + (lane&15)]   (0 if col >= JW)
__global__ __launch_bounds__(256) void k_prep(const float* __restrict__ W1,
                                              const float* __restrict__ W2,
                                              unsigned short* __restrict__ wp1,
                                              unsigned short* __restrict__ wp2) {
    int tid = threadIdx.x;
    for (int i = tid; i < 4096; i += 256) {           // 2 kk * 4 jt * 64 lane * 8 e
        int e = i & 7, lane = (i >> 3) & 63, t = i >> 9;
        int kk = t >> 2, jt = t & 3;
        int row = kk * 32 + (lane >> 4) * 8 + e;
        int col = jt * 16 + (lane & 15);
        wp1[i] = f2b(W1[row * 64 + col]);
    }
    for (int i = tid; i < 3072; i += 256) {           // 2 kk * 3 jt * 64 lane * 8 e
        int e = i & 7, lane = (i >> 3) & 63, t = i >> 9;
        int kk = t / 3, jt = t - kk * 3;
        int row = kk * 32 + (lane >> 4) * 8 + e;
        int col = jt * 16 + (lane & 15);
        wp2[i] = (col < 40) ? f2b(W2[row * 40 + col]) : (unsigned short)0;
    }
}

// ---- layer1 GEMM via MFMA: gb[v][j] = bf16(dinv[v] * (x @ W1)[v][j]) ----
// Wave computes 16 nodes x 64 cols. D = A(W^T) * B(x^T): D col = node, row = j.
__global__ __launch_bounds__(256) void k_gemm1m(const float* __restrict__ x,
                                                const short8* __restrict__ wp,
                                                const float* __restrict__ dinv,
                                                unsigned short* __restrict__ gb) {
    int lane = threadIdx.x & 63;
    int wid = threadIdx.x >> 6;
    int node0 = (blockIdx.x * 4 + wid) * 16;
    if (node0 >= N_NODES) return;
    int vr = node0 + (lane & 15);
    if (vr >= N_NODES) vr = N_NODES - 1;               // defensive (unreachable)
    int kg = lane >> 4;
    const float* px = x + (size_t)vr * 64 + kg * 8;
    short8 b0, b1;
    {
        float4 f0 = *(const float4*)px;
        float4 f1 = *(const float4*)(px + 4);
        b0[0] = (short)f2b(f0.x); b0[1] = (short)f2b(f0.y);
        b0[2] = (short)f2b(f0.z); b0[3] = (short)f2b(f0.w);
        b0[4] = (short)f2b(f1.x); b0[5] = (short)f2b(f1.y);
        b0[6] = (short)f2b(f1.z); b0[7] = (short)f2b(f1.w);
        float4 g0 = *(const float4*)(px + 32);
        float4 g1 = *(const float4*)(px + 36);
        b1[0] = (short)f2b(g0.x); b1[1] = (short)f2b(g0.y);
        b1[2] = (short)f2b(g0.z); b1[3] = (short)f2b(g0.w);
        b1[4] = (short)f2b(g1.x); b1[5] = (short)f2b(g1.y);
        b1[6] = (short)f2b(g1.z); b1[7] = (short)f2b(g1.w);
    }
    f32x4 acc[4];
#pragma unroll
    for (int jt = 0; jt < 4; jt++) acc[jt] = (f32x4){0.f, 0.f, 0.f, 0.f};
#pragma unroll
    for (int jt = 0; jt < 4; jt++) {
        acc[jt] = __builtin_amdgcn_mfma_f32_16x16x32_bf16(
            wp[(0 * 4 + jt) * 64 + lane], b0, acc[jt], 0, 0, 0);
        acc[jt] = __builtin_amdgcn_mfma_f32_16x16x32_bf16(
            wp[(1 * 4 + jt) * 64 + lane], b1, acc[jt], 0, 0, 0);
    }
    float d = dinv[vr];
    unsigned short* gp = gb + (size_t)vr * 64 + kg * 4;
#pragma unroll
    for (int jt = 0; jt < 4; jt++) {
        unsigned int lo = (unsigned int)f2b(acc[jt][0] * d) |
                          ((unsigned int)f2b(acc[jt][1] * d) << 16);
        unsigned int hi = (unsigned int)f2b(acc[jt][2] * d) |
                          ((unsigned int)f2b(acc[jt][3] * d) << 16);
        *(uint2*)(gp + jt * 16) = make_uint2(lo, hi);
    }
}

// ---- layer2 GEMM via MFMA: gb[v][j<40] = bf16(dinv[v] * (h @ W2)[v][j]) ----
// h is bf16 (hb), so B-fragments are direct 16B loads.
__global__ __launch_bounds__(256) void k_gemm2m(const unsigned short* __restrict__ hb,
                                                const short8* __restrict__ wp,
                                                const float* __restrict__ dinv,
                                                unsigned short* __restrict__ gb) {
    int lane = threadIdx.x & 63;
    int wid = threadIdx.x >> 6;
    int node0 = (blockIdx.x * 4 + wid) * 16;
    if (node0 >= N_NODES) return;
    int vr = node0 + (lane & 15);
    if (vr >= N_NODES) vr = N_NODES - 1;
    int kg = lane >> 4;
    const short8* h8 = (const short8*)hb;
    short8 b0 = h8[(size_t)vr * 8 + kg];
    short8 b1 = h8[(size_t)vr * 8 + 4 + kg];
    f32x4 acc[3];
#pragma unroll
    for (int jt = 0; jt < 3; jt++) acc[jt] = (f32x4){0.f, 0.f, 0.f, 0.f};
#pragma unroll
    for (int jt = 0; jt < 3; jt++) {
        acc[jt] = __builtin_amdgcn_mfma_f32_16x16x32_bf16(
            wp[(0 * 3 + jt) * 64 + lane], b0, acc[jt], 0, 0, 0);
        acc[jt] = __builtin_amdgcn_mfma_f32_16x16x32_bf16(
            wp[(1 * 3 + jt) * 64 + lane], b1, acc[jt], 0, 0, 0);
    }
    float d = dinv[vr];
    unsigned short* gp = gb + (size_t)vr * 40 + kg * 4;
#pragma unroll
    for (int jt = 0; jt < 3; jt++) {
        if (jt == 2 && kg >= 2) break;                 // j >= 40
        unsigned int lo = (unsigned int)f2b(acc[jt][0] * d) |
                          ((unsigned int)f2b(acc[jt][1] * d) << 16);
        unsigned int hi = (unsigned int)f2b(acc[jt][2] * d) |
                          ((unsigned int)f2b(acc[jt][3] * d) << 16);
        *(uint2*)(gp + jt * 16) = make_uint2(lo, hi);
    }
}

// ---- agg1: 8-lane edge-groups, uint4 (8xbf16) gathers. BRANCH-FREE gather:
//      clamped addresses, unconditional loads, w in {0,1} FMA predication;
//      trip count rounded to 4 and manually unrolled -> 4 loads in flight.
//      bias + ReLU -> hb (bf16) ----
__global__ __launch_bounds__(256) void k_agg1(const int* __restrict__ csr,
                                              const int* __restrict__ start,
                                              const unsigned int* __restrict__ gb2,
                                              const float* __restrict__ dinv,
                                              const float* __restrict__ b1,
                                              unsigned short* __restrict__ hb) {
    int lane = threadIdx.x & 63;
    int g = lane >> 3;          // 8 edge-groups of 8 lanes; group g -> edges 8*k+g
    int lq = lane & 7;          // 16B slice lq of the 128B row (cols 8lq..8lq+7)
    int v = blockIdx.x * 4 + (threadIdx.x >> 6);
    int s = start[v], e2 = start[v + 1];
    int deg = e2 - s;
    float a0=0.f,a1=0.f,a2=0.f,a3=0.f,a4=0.f,a5=0.f,a6=0.f,a7=0.f;
    if (g == 0) {               // self-loop contribution
        uint4 u = *(const uint4*)(gb2 + (size_t)v * 32 + lq * 4);
        a0 += bflo(u.x); a1 += bfhi(u.x); a2 += bflo(u.y); a3 += bfhi(u.y);
        a4 += bflo(u.z); a5 += bfhi(u.z); a6 += bflo(u.w); a7 += bfhi(u.w);
    }
    int nk = (deg + 7) >> 3;
    int nkr = (nk + 3) & ~3;    // wave-uniform, multiple of 4
    for (int k = 0; k < nkr; k += 4) {
#pragma unroll
        for (int kk = 0; kk < 4; kk++) {
            int idx = (k + kk) * 8 + g;
            bool p = idx < deg;
            int r = csr[s + (p ? idx : 0)];            // clamped, unconditional
            uint4 u = *(const uint4*)(gb2 + (size_t)r * 32 + lq * 4);
            float w = p ? 1.f : 0.f;                   // finite data: 0*val == 0
            a0 = fmaf(w, bflo(u.x), a0); a1 = fmaf(w, bfhi(u.x), a1);
            a2 = fmaf(w, bflo(u.y), a2); a3 = fmaf(w, bfhi(u.y), a3);
            a4 = fmaf(w, bflo(u.z), a4); a5 = fmaf(w, bfhi(u.z), a5);
            a6 = fmaf(w, bflo(u.w), a6); a7 = fmaf(w, bfhi(u.w), a7);
        }
    }
    // fold the 8 edge-groups (all 64 lanes active at every shfl)
#pragma unroll
    for (int o = 8; o < 64; o <<= 1) {
        a0 += __shfl_xor(a0, o, 64); a1 += __shfl_xor(a1, o, 64);
        a2 += __shfl_xor(a2, o, 64); a3 += __shfl_xor(a3, o, 64);
        a4 += __shfl_xor(a4, o, 64); a5 += __shfl_xor(a5, o, 64);
        a6 += __shfl_xor(a6, o, 64); a7 += __shfl_xor(a7, o, 64);
    }
    float d = dinv[v];
    float4 bb0 = ((const float4*)b1)[lq * 2];
    float4 bb1 = ((const float4*)b1)[lq * 2 + 1];
    float h0 = fmaxf(d * a0 + bb0.x, 0.f), h1 = fmaxf(d * a1 + bb0.y, 0.f);
    float h2 = fmaxf(d * a2 + bb0.z, 0.f), h3 = fmaxf(d * a3 + bb0.w, 0.f);
    float h4 = fmaxf(d * a4 + bb1.x, 0.f), h5 = fmaxf(d * a5 + bb1.y, 0.f);
    float h6 = fmaxf(d * a6 + bb1.z, 0.f), h7 = fmaxf(d * a7 + bb1.w, 0.f);
    if (g == 0) {
        uint4 o;
        o.x = (unsigned int)f2b(h0) | ((unsigned int)f2b(h1) << 16);
        o.y = (unsigned int)f2b(h2) | ((unsigned int)f2b(h3) << 16);
        o.z = (unsigned int)f2b(h4) | ((unsigned int)f2b(h5) << 16);
        o.w = (unsigned int)f2b(h6) | ((unsigned int)f2b(h7) << 16);
        *(uint4*)(hb + (size_t)v * 64 + lq * 8) = o;
    }
}

// ---- agg2: 8-lane edge-groups (5 active: 5x16B = 80B row). BRANCH-FREE
//      gather (clamped idx AND clamped slice for idle lanes -> no extra
//      cache lines); fused bias + log_softmax -> out ----
__global__ __launch_bounds__(256) void k_agg2(const int* __restrict__ csr,
                                              const int* __restrict__ start,
                                              const unsigned int* __restrict__ g2b2,
                                              const float* __restrict__ dinv,
                                              const float* __restrict__ b2v,
                                              float* __restrict__ out) {
    int lane = threadIdx.x & 63;
    int g = lane >> 3;          // 8 edge-groups of 8 lanes
    int lq = lane & 7;          // 16B slice of the 80B row; active lq<5
    int v = blockIdx.x * 4 + (threadIdx.x >> 6);
    int s = start[v], e2 = start[v + 1];
    int deg = e2 - s;
    bool act = (lq < 5);
    int lqc = act ? lq : 0;     // idle lanes alias slice 0 (same line, dedup'd)
    float a0=0.f,a1=0.f,a2=0.f,a3=0.f,a4=0.f,a5=0.f,a6=0.f,a7=0.f;
    if (g == 0 && act) {        // self-loop contribution
        uint4 u = *(const uint4*)(g2b2 + (size_t)v * 20 + lq * 4);
        a0 += bflo(u.x); a1 += bfhi(u.x); a2 += bflo(u.y); a3 += bfhi(u.y);
        a4 += bflo(u.z); a5 += bfhi(u.z); a6 += bflo(u.w); a7 += bfhi(u.w);
    }
    int nk = (deg + 7) >> 3;
    int nkr = (nk + 3) & ~3;    // wave-uniform, multiple of 4
    for (int k = 0; k < nkr; k += 4) {
#pragma unroll
        for (int kk = 0; kk < 4; kk++) {
            int idx = (k + kk) * 8 + g;
            bool pi = idx < deg;
            int r = csr[s + (pi ? idx : 0)];           // clamped, unconditional
            uint4 u = *(const uint4*)(g2b2 + (size_t)r * 20 + lqc * 4);
            float w = (pi && act) ? 1.f : 0.f;         // finite data: 0*val == 0
            a0 = fmaf(w, bflo(u.x), a0); a1 = fmaf(w, bfhi(u.x), a1);
            a2 = fmaf(w, bflo(u.y), a2); a3 = fmaf(w, bfhi(u.y), a3);
            a4 = fmaf(w, bflo(u.z), a4); a5 = fmaf(w, bfhi(u.z), a5);
            a6 = fmaf(w, bflo(u.w), a6); a7 = fmaf(w, bfhi(u.w), a7);
        }
    }
    // fold the 8 edge-groups (all 64 lanes active at every shfl)
#pragma unroll
    for (int o = 8; o < 64; o <<= 1) {
        a0 += __shfl_xor(a0, o, 64); a1 += __shfl_xor(a1, o, 64);
        a2 += __shfl_xor(a2, o, 64); a3 += __shfl_xor(a3, o, 64);
        a4 += __shfl_xor(a4, o, 64); a5 += __shfl_xor(a5, o, 64);
        a6 += __shfl_xor(a6, o, 64); a7 += __shfl_xor(a7, o, 64);
    }
    float d = dinv[v];
    float4 bb0 = act ? ((const float4*)b2v)[lq * 2] : make_float4(0.f,0.f,0.f,0.f);
    float4 bb1 = act ? ((const float4*)b2v)[lq * 2 + 1] : make_float4(0.f,0.f,0.f,0.f);
    float l0 = act ? d * a0 + bb0.x : -INFINITY;
    float l1 = act ? d * a1 + bb0.y : -INFINITY;
    float l2 = act ? d * a2 + bb0.z : -INFINITY;
    float l3 = act ? d * a3 + bb0.w : -INFINITY;
    float l4 = act ? d * a4 + bb1.x : -INFINITY;
    float l5 = act ? d * a5 + bb1.y : -INFINITY;
    float l6 = act ? d * a6 + bb1.z : -INFINITY;
    float l7 = act ? d * a7 + bb1.w : -INFINITY;
    float m = fmaxf(fmaxf(fmaxf(l0, l1), fmaxf(l2, l3)),
                    fmaxf(fmaxf(l4, l5), fmaxf(l6, l7)));
#pragma unroll
    for (int o = 1; o < 8; o <<= 1) m = fmaxf(m, __shfl_xor(m, o, 64));
    float ex = act ? (__expf(l0 - m) + __expf(l1 - m) + __expf(l2 - m) +
                      __expf(l3 - m) + __expf(l4 - m) + __expf(l5 - m) +
                      __expf(l6 - m) + __expf(l7 - m)) : 0.f;
#pragma unroll
    for (int o = 1; o < 8; o <<= 1) ex += __shfl_xor(ex, o, 64);
    float lse = m + logf(ex);
    if (g == 0 && act) {
        float* op = out + (size_t)v * 40 + lq * 8;
        *(float4*)op = make_float4(l0 - lse, l1 - lse, l2 - lse, l3 - lse);
        *(float4*)(op + 4) = make_float4(l4 - lse, l5 - lse, l6 - lse, l7 - lse);
    }
}

extern "C" void kernel_launch(void* const* d_in, const int* in_sizes, int n_in,
                              void* d_out, int out_size, void* d_ws, size_t ws_size,
                              hipStream_t stream) {
    const float* x  = (const float*)d_in[0];
    const int*   ei = (const int*)d_in[1];
    const float* W1 = (const float*)d_in[2];
    const float* b1 = (const float*)d_in[3];
    const float* W2 = (const float*)d_in[4];
    const float* b2 = (const float*)d_in[5];
    float* out = (float*)d_out;

    const int N = N_NODES;
    // Workspace layout (ints from base), total ~39.3 MB:
    int*   part  = (int*)d_ws;                  // E      packed partitioned edges
    int*   csr   = part + N_EDGES;              // E
    int*   start = csr + N_EDGES;               // N+2 (padded even)
    int*   bcnt  = start + N + 2;               // 256*16 padded counters
    int*   fill  = bcnt + 4096;                 // 256*16 padded counters
    int*   bbase = fill + 4096;                 // 257 (+pad -> 258)
    float* dinv  = (float*)(bbase + 258);       // N (16B-aligned)
    unsigned short* hb  = (unsigned short*)(dinv + N);   // N*64 bf16 (16B-aligned)
    unsigned short* gb  = hb + (size_t)N * 64;           // N*64 bf16 (g1; reused g2 N*40)
    unsigned short* wp1 = gb + (size_t)N * 64;           // 4096 bf16 W1 fragments
    unsigned short* wp2 = wp1 + 4096;                    // 3072 bf16 W2 fragments

    k_zero<<<16, 256, 0, stream>>>(bcnt, 4096);
    k_prep<<<1, 256, 0, stream>>>(W1, W2, wp1, wp2);
    k_cnt<<<256, 256, 0, stream>>>(ei + N_EDGES, bcnt);
    k_scan256<<<1, 256, 0, stream>>>(bcnt, fill, bbase);
    k_place<<<P3_GRID, 256, 0, stream>>>(ei, fill, part);
    k_build<<<NBUCK, 256, 0, stream>>>(part, bbase, start, dinv, csr);
    k_gemm1m<<<GEMM_GRID, 256, 0, stream>>>(x, (const short8*)wp1, dinv, gb);
    k_agg1<<<N / 4, 256, 0, stream>>>(csr, start, (const unsigned int*)gb, dinv, b1, hb);
    k_gemm2m<<<GEMM_GRID, 256, 0, stream>>>(hb, (const short8*)wp2, dinv, gb);
    k_agg2<<<N / 4, 256, 0, stream>>>(csr, start, (const unsigned int*)gb, dinv, b2, out);
}